// Round 5
// baseline (297.667 us; speedup 1.0000x reference)
//
#include <hip/hip_runtime.h>
#include <hip/hip_bf16.h>

// ScaledDotProductAttention: B=2 H=16 S=2048 DK=64, fp32 in, outputs
// (attn_out [B,H,S,DK], weights [B,H,S,S]) concatenated in d_out (fp32).
//
// R5: R4 + nontemporal-store fix (ext_vector_type, not HIP float4 struct).
// Swapped QK^T (mfma(K,Q) -> S^T in regs): each lane holds 4 CONSECUTIVE
// k for one q row -> W stores become global_store_dwordx4 (8/thread/tile vs
// 32 scalar), Ps writes become ds_write_b64 (8 vs 32), mask loads 2 uint2 vs
// 8. launch_bounds(256,3) for 3 blocks/CU. Rest as R3: 1 barrier/tile,
// double-buffered K/V, T14 issue-early/write-late, fixed m=0, nt stores.

namespace {

constexpr int Bc = 2, Hc = 16, Sc = 2048, Dc = 64;
constexpr int QT = 128;            // q rows per block (4 waves x 32)
constexpr int KT = 64;             // kv cols per tile
constexpr int NKV = Sc / KT;       // 32
constexpr int NQB = Sc / QT;       // 16
constexpr int NBH = Bc * Hc;       // 32
constexpr float SCALE2 = 0.125f * 1.44269504088896340736f; // (1/sqrt(64))*log2(e)

// LDS byte offsets (total 48 KB)
constexpr int PS_OFF = 0;          // 16 KB bf16[128][64] (aliases Q staging)
constexpr int KS_OFF = 16384;      // 2 x 8 KB, select via (kv&1)*8192
constexpr int VS_OFF = 32768;      // 2 x 8 KB (transposed), same select

using short8 = __attribute__((ext_vector_type(8))) short;  // 8 bf16 (4 VGPR)
using f32x4  = __attribute__((ext_vector_type(4))) float;  // MFMA acc / nt-store

// XOR swizzle for 64-col bf16 rows (128B stride): bank-conflict fix (G4).
__device__ __forceinline__ int swz(int row, int bytecol) {
    return row * 128 + (bytecol ^ ((row & 7) << 4));
}

// fp32 -> bf16 round-to-nearest-even
__device__ __forceinline__ unsigned short f2b(float f) {
    unsigned u = __float_as_uint(f);
    unsigned r = (u + 0x7fffu + ((u >> 16) & 1u)) >> 16;
    return (unsigned short)r;
}
__device__ __forceinline__ unsigned pk2(float a, float b) {
    return (unsigned)f2b(a) | ((unsigned)f2b(b) << 16);
}

__device__ __forceinline__ f32x4 mfma16(short8 a, short8 b, f32x4 c) {
    return __builtin_amdgcn_mfma_f32_16x16x32_bf16(a, b, c, 0, 0, 0);
}
__device__ __forceinline__ short8 ldlds(const char* lds, int off, int row,
                                        int bytecol) {
    return *reinterpret_cast<const short8*>(lds + off + swz(row, bytecol));
}

// ---- staging helpers (16KB f32 tile -> 8KB bf16 swizzled LDS) ----
__device__ __forceinline__ void ld_k(const float* __restrict__ src, int t,
                                     float4 reg[4]) {
    #pragma unroll
    for (int i = 0; i < 4; ++i) {
        int ch = t + 256 * i;                  // 0..1023
        int r = ch >> 4, d0 = (ch & 15) << 2;
        reg[i] = *reinterpret_cast<const float4*>(src + (size_t)r * Dc + d0);
    }
}
__device__ __forceinline__ void st_k(char* lds, int off, int t,
                                     const float4 reg[4]) {
    #pragma unroll
    for (int i = 0; i < 4; ++i) {
        int ch = t + 256 * i;
        int r = ch >> 4, d0 = (ch & 15) << 2;
        uint2 pk; pk.x = pk2(reg[i].x, reg[i].y); pk.y = pk2(reg[i].z, reg[i].w);
        *reinterpret_cast<uint2*>(lds + off + swz(r, d0 * 2)) = pk;
    }
}
// V tile loaded row-major, stored TRANSPOSED (rows = d, cols = kv pos)
__device__ __forceinline__ void ld_v(const float* __restrict__ src, int t,
                                     float4 reg[4]) {
    int d0 = (t & 15) << 2, c0 = (t >> 4) << 2;
    #pragma unroll
    for (int i = 0; i < 4; ++i)
        reg[i] = *reinterpret_cast<const float4*>(src + (size_t)(c0 + i) * Dc + d0);
}
__device__ __forceinline__ void st_v(char* lds, int off, int t,
                                     const float4 reg[4]) {
    int d0 = (t & 15) << 2, c0 = (t >> 4) << 2;
    uint2 pk;
    pk.x = pk2(reg[0].x, reg[1].x); pk.y = pk2(reg[2].x, reg[3].x);
    *reinterpret_cast<uint2*>(lds + off + swz(d0 + 0, c0 * 2)) = pk;
    pk.x = pk2(reg[0].y, reg[1].y); pk.y = pk2(reg[2].y, reg[3].y);
    *reinterpret_cast<uint2*>(lds + off + swz(d0 + 1, c0 * 2)) = pk;
    pk.x = pk2(reg[0].z, reg[1].z); pk.y = pk2(reg[2].z, reg[3].z);
    *reinterpret_cast<uint2*>(lds + off + swz(d0 + 2, c0 * 2)) = pk;
    pk.x = pk2(reg[0].w, reg[1].w); pk.y = pk2(reg[2].w, reg[3].w);
    *reinterpret_cast<uint2*>(lds + off + swz(d0 + 3, c0 * 2)) = pk;
}

// ---- mask prepack: 1 bit per element via wave ballot ----
__global__ __launch_bounds__(256) void pack_mask(
    const int* __restrict__ Mg, unsigned long long* __restrict__ bits)
{
    int tg = blockIdx.x * 256 + threadIdx.x;        // over S*S
    int v = Mg[tg];
    unsigned long long b = __ballot(v != 0);
    if ((threadIdx.x & 63) == 0) bits[tg >> 6] = b;
}

template <bool USE_BITS>
__global__ __launch_bounds__(256, 3)
void attn_main(const float* __restrict__ Qg, const float* __restrict__ Kg,
               const float* __restrict__ Vg, const int* __restrict__ Mg,
               const unsigned* __restrict__ mbits,
               float* __restrict__ Og, float* __restrict__ Wg)
{
    __shared__ char lds_s[49152];
    char* lds = lds_s;   // decay once; all accesses via integer offsets

    // XCD-grouped mapping: 4 bh per XCD -> K/V stay L2-resident per XCD.
    const int bid = blockIdx.x;                 // 0..511
    const int xcd = bid & 7, idx = bid >> 3;    // idx 0..63
    const int bh  = xcd * 4 + (idx & 3);        // 0..31
    const int qb  = idx >> 2;                   // 0..15

    const int t    = threadIdx.x;
    const int lane = t & 63;
    const int w    = t >> 6;                    // wave 0..3
    const int l15  = lane & 15, hi4 = lane >> 4;
    const int qw   = 32 * w;                    // wave's first q row in block

    const size_t bh_off = (size_t)bh * Sc * Dc;
    const float* Qb = Qg + bh_off + (size_t)qb * QT * Dc;
    const float* Kb = Kg + bh_off;
    const float* Vb = Vg + bh_off;
    float* Ob = Og + bh_off + (size_t)qb * QT * Dc;
    float* Wb = Wg + (size_t)bh * Sc * Sc + (size_t)qb * QT * Sc;

    // the two q rows this thread owns in S^T layout (one per qt)
    const int ql0 = qw + l15;          // qt=0
    const int ql1 = qw + 16 + l15;     // qt=1
    const int qg0 = qb * QT + ql0;
    const int qg1 = qb * QT + ql1;

    // ---- stage Q (into Ps area) + K tile 0; one barrier ----
    #pragma unroll
    for (int i = 0; i < 8; ++i) {
        int ch = t + 256 * i;                   // 0..2047
        int r = ch >> 4, d0 = (ch & 15) << 2;
        float4 v = *reinterpret_cast<const float4*>(Qb + (size_t)r * Dc + d0);
        uint2 pk; pk.x = pk2(v.x, v.y); pk.y = pk2(v.z, v.w);
        *reinterpret_cast<uint2*>(lds + PS_OFF + swz(r, d0 * 2)) = pk;
    }
    {
        float4 kreg[4];
        ld_k(Kb, t, kreg);
        st_k(lds, KS_OFF, t, kreg);
    }
    __syncthreads();

    // ---- hoist Q fragments to registers (frees Ps area for pass 2) ----
    short8 qf[2][2];
    #pragma unroll
    for (int qt = 0; qt < 2; ++qt)
        #pragma unroll
        for (int kk = 0; kk < 2; ++kk)
            qf[qt][kk] = ldlds(lds, PS_OFF, qw + qt * 16 + l15,
                               kk * 64 + hi4 * 16);

    float lsum0 = 0.f, lsum1 = 0.f;

    // ================= pass 1: row sums only (fixed m = 0) =================
    for (int kv = 0; kv < NKV; ++kv) {
        const int nx = (kv + 1) & (NKV - 1);    // wraps to 0 -> preload pass 2
        const int cko = KS_OFF + (kv & 1) * 8192;
        float4 kreg[4], vreg[4];
        ld_k(Kb + (size_t)nx * KT * Dc, t, kreg);       // issue early (T14)
        if (kv == NKV - 1) ld_v(Vb, t, vreg);           // preload V tile 0

        uint2 mb0, mb1;
        if (USE_BITS) {
            mb0 = *reinterpret_cast<const uint2*>(mbits + (size_t)qg0 * 64 + kv * 2);
            mb1 = *reinterpret_cast<const uint2*>(mbits + (size_t)qg1 * 64 + kv * 2);
        }

        // swapped QK^T: sc[qt][ct] = S^T block; lane holds
        // k = kv*64 + ct*16 + hi4*4 + r,  q = qw + qt*16 + l15
        f32x4 sc[2][4];
        #pragma unroll
        for (int qt = 0; qt < 2; ++qt)
            #pragma unroll
            for (int ct = 0; ct < 4; ++ct) sc[qt][ct] = f32x4{0.f, 0.f, 0.f, 0.f};
        #pragma unroll
        for (int kk = 0; kk < 2; ++kk) {
            int bc = kk * 64 + hi4 * 16;
            #pragma unroll
            for (int ct = 0; ct < 4; ++ct) {
                short8 kf = ldlds(lds, cko, ct * 16 + l15, bc);
                sc[0][ct] = mfma16(kf, qf[0][kk], sc[0][ct]);
                sc[1][ct] = mfma16(kf, qf[1][kk], sc[1][ct]);
            }
        }

        #pragma unroll
        for (int qt = 0; qt < 2; ++qt) {
            unsigned wlo = 0, whi = 0;
            if (USE_BITS) {
                wlo = qt ? mb1.x : mb0.x;
                whi = qt ? mb1.y : mb0.y;
            }
            int qg = qt ? qg1 : qg0;
            float acc = 0.f;
            #pragma unroll
            for (int ct = 0; ct < 4; ++ct) {
                unsigned word = (ct >= 2) ? whi : wlo;
                #pragma unroll
                for (int r = 0; r < 4; ++r) {
                    float sv = sc[qt][ct][r] * SCALE2;
                    bool keep;
                    if (USE_BITS)
                        keep = (word >> ((ct & 1) * 16 + hi4 * 4 + r)) & 1;
                    else
                        keep = Mg[(size_t)qg * Sc + kv * KT + ct * 16 + hi4 * 4 + r] != 0;
                    acc += keep ? exp2f(sv) : 0.0f;
                }
            }
            if (qt) lsum1 += acc; else lsum0 += acc;
        }

        // write-late: next K tile (and V tile 0 at the wrap)
        st_k(lds, KS_OFF + (nx & 1) * 8192, t, kreg);
        if (kv == NKV - 1) st_v(lds, VS_OFF, t, vreg);
        __syncthreads();
    }

    // cross-lane merge over the 4 hi4 groups (each holds a k-quarter)
    float rls0, rls1;
    {
        float s = lsum0;
        s += __shfl_xor(s, 16);
        s += __shfl_xor(s, 32);
        rls0 = 1.0f / s;
        s = lsum1;
        s += __shfl_xor(s, 16);
        s += __shfl_xor(s, 32);
        rls1 = 1.0f / s;
    }

    // ================= pass 2: W write + PV =================
    f32x4 oa[2][4];
    #pragma unroll
    for (int qt = 0; qt < 2; ++qt)
        #pragma unroll
        for (int dt = 0; dt < 4; ++dt) oa[qt][dt] = f32x4{0.f, 0.f, 0.f, 0.f};

    for (int kv = 0; kv < NKV; ++kv) {
        const bool pf = (kv + 1) < NKV;
        const int cko = KS_OFF + (kv & 1) * 8192;
        const int cvo = VS_OFF + (kv & 1) * 8192;
        float4 kreg[4], vreg[4];
        if (pf) {
            ld_k(Kb + (size_t)(kv + 1) * KT * Dc, t, kreg);
            ld_v(Vb + (size_t)(kv + 1) * KT * Dc, t, vreg);
        }

        uint2 mb0, mb1;
        if (USE_BITS) {
            mb0 = *reinterpret_cast<const uint2*>(mbits + (size_t)qg0 * 64 + kv * 2);
            mb1 = *reinterpret_cast<const uint2*>(mbits + (size_t)qg1 * 64 + kv * 2);
        }

        // swapped QK^T (recompute)
        f32x4 sc[2][4];
        #pragma unroll
        for (int qt = 0; qt < 2; ++qt)
            #pragma unroll
            for (int ct = 0; ct < 4; ++ct) sc[qt][ct] = f32x4{0.f, 0.f, 0.f, 0.f};
        #pragma unroll
        for (int kk = 0; kk < 2; ++kk) {
            int bc = kk * 64 + hi4 * 16;
            #pragma unroll
            for (int ct = 0; ct < 4; ++ct) {
                short8 kf = ldlds(lds, cko, ct * 16 + l15, bc);
                sc[0][ct] = mfma16(kf, qf[0][kk], sc[0][ct]);
                sc[1][ct] = mfma16(kf, qf[1][kk], sc[1][ct]);
            }
        }

        // weights: lane owns 4 consecutive k of one q row -> float4 stores
        #pragma unroll
        for (int qt = 0; qt < 2; ++qt) {
            unsigned wlo = 0, whi = 0;
            if (USE_BITS) {
                wlo = qt ? mb1.x : mb0.x;
                whi = qt ? mb1.y : mb0.y;
            }
            int ql = qt ? ql1 : ql0;
            int qg = qt ? qg1 : qg0;
            float rl = qt ? rls1 : rls0;
            float* wrow = Wb + (size_t)ql * Sc + kv * KT;
            #pragma unroll
            for (int ct = 0; ct < 4; ++ct) {
                unsigned word = (ct >= 2) ? whi : wlo;
                float p[4];
                #pragma unroll
                for (int r = 0; r < 4; ++r) {
                    float sv = sc[qt][ct][r] * SCALE2;
                    bool keep;
                    if (USE_BITS)
                        keep = (word >> ((ct & 1) * 16 + hi4 * 4 + r)) & 1;
                    else
                        keep = Mg[(size_t)qg * Sc + kv * KT + ct * 16 + hi4 * 4 + r] != 0;
                    p[r] = keep ? exp2f(sv) * rl : 0.0f;
                }
                // Ps (bf16, wave-local rows): one ds_write_b64
                uint2 pp; pp.x = pk2(p[0], p[1]); pp.y = pk2(p[2], p[3]);
                *reinterpret_cast<uint2*>(
                    lds + PS_OFF + swz(ql, ct * 32 + hi4 * 8)) = pp;
                // W: one nontemporal dwordx4 (16B; ext-vector type for builtin)
                f32x4 wv = { p[0], p[1], p[2], p[3] };
                __builtin_nontemporal_store(
                    wv, reinterpret_cast<f32x4*>(wrow + ct * 16 + hi4 * 4));
            }
        }
        // no barrier: Ps rows are wave-local; same-wave DS ops are in-order.

        // PV: oa += P(bf16) * V^T(bf16)
        #pragma unroll
        for (int kk = 0; kk < 2; ++kk) {
            int bc = kk * 64 + hi4 * 16;       // k = kk*32 + hi4*8 + e
            short8 a0 = ldlds(lds, PS_OFF, qw + l15, bc);
            short8 a1 = ldlds(lds, PS_OFF, qw + 16 + l15, bc);
            #pragma unroll
            for (int dt = 0; dt < 4; ++dt) {
                short8 b = ldlds(lds, cvo, dt * 16 + l15, bc);
                oa[0][dt] = mfma16(a0, b, oa[0][dt]);
                oa[1][dt] = mfma16(a1, b, oa[1][dt]);
            }
        }

        // write-late staging for next tile, then the single barrier
        if (pf) {
            st_k(lds, KS_OFF + ((kv + 1) & 1) * 8192, t, kreg);
            st_v(lds, VS_OFF + ((kv + 1) & 1) * 8192, t, vreg);
        }
        __syncthreads();
    }

    // epilogue: store O (nontemporal, coalesced; once per kernel)
    #pragma unroll
    for (int qt = 0; qt < 2; ++qt)
        #pragma unroll
        for (int dt = 0; dt < 4; ++dt)
            #pragma unroll
            for (int r = 0; r < 4; ++r) {
                int ql = qw + qt * 16 + hi4 * 4 + r;
                __builtin_nontemporal_store(
                    oa[qt][dt][r], Ob + (size_t)ql * Dc + dt * 16 + l15);
            }
}

} // namespace

extern "C" void kernel_launch(void* const* d_in, const int* in_sizes, int n_in,
                              void* d_out, int out_size, void* d_ws, size_t ws_size,
                              hipStream_t stream) {
    const float* Qg = (const float*)d_in[0];
    const float* Kg = (const float*)d_in[1];
    const float* Vg = (const float*)d_in[2];
    const int*   Mg = (const int*)d_in[3];
    float* out_o = (float*)d_out;
    float* out_w = out_o + (size_t)Bc * Hc * Sc * Dc;   // weights after output

    const size_t bits_bytes = (size_t)Sc * Sc / 8;      // 512 KB
    const bool use_bits = (d_ws != nullptr) && (ws_size >= bits_bytes);

    dim3 grid(NQB * NBH), blk(256);
    if (use_bits) {
        pack_mask<<<(Sc * Sc) / 256, 256, 0, stream>>>(
            Mg, (unsigned long long*)d_ws);
        attn_main<true><<<grid, blk, 0, stream>>>(
            Qg, Kg, Vg, Mg, (const unsigned*)d_ws, out_o, out_w);
    } else {
        attn_main<false><<<grid, blk, 0, stream>>>(
            Qg, Kg, Vg, Mg, nullptr, out_o, out_w);
    }
}